// Round 7
// baseline (334.049 us; speedup 1.0000x reference)
//
#include <hip/hip_runtime.h>

#define NN 50000
#define NN0 30000
#define NN1 20000
#define NE 600000
#define INC 128
#define HIDC 128
#define OUTC 40
#define RS 1152      // A row stride in bf16 elems: 8*128 agg + 128 feat
#define RSB 2304     // row stride bytes
#define KST 36       // K steps of 32 (1152/32)
#define KH 18        // K-steps per K-half
#define CAP 64       // bucket capacity per dst
#define OVCAP 65536
#define XB 3125      // xbuild blocks (NN*16/256)
#define FB 2344      // fill blocks (ceil(NE/256))
#define PB 198       // pack blocks ((2*36*8*64 + 2*36*3*64)/256)

typedef __attribute__((ext_vector_type(4))) float f32x4;
typedef __attribute__((ext_vector_type(8))) short s16x8;

static __device__ __forceinline__ unsigned short f2bf(float f){
  unsigned u = __builtin_bit_cast(unsigned, f);
  u = u + 0x7fffu + ((u >> 16) & 1u);
  return (unsigned short)(u >> 16);
}
static __device__ __forceinline__ float bflo(unsigned w){
  return __builtin_bit_cast(float, w << 16);
}
static __device__ __forceinline__ float bfhi(unsigned w){
  return __builtin_bit_cast(float, w & 0xffff0000u);
}

// fused grid: [0,XB) gather features -> A tail; [XB,XB+FB) bucket edges;
//             [XB+FB,XB+FB+PB) pack B1/B2.
__global__ void build_k(const float* __restrict__ x0, const float* __restrict__ e1,
                        const int* __restrict__ ntp, const int* __restrict__ lix,
                        char* __restrict__ A,
                        const int* __restrict__ ei, const int* __restrict__ et,
                        int* __restrict__ deg, int* __restrict__ eb,
                        int* __restrict__ ovf, int* __restrict__ ovc,
                        const float* __restrict__ rw1, const float* __restrict__ qw1,
                        const float* __restrict__ rw2, const float* __restrict__ qw2,
                        short* __restrict__ Bp1, short* __restrict__ Bp2){
  int b = blockIdx.x;
  if(b < XB){
    int tid = b * 256 + threadIdx.x;   // NN*16
    int n = tid >> 4, q = tid & 15;
    if(n >= NN) return;
    int t = ntp[n], li = lix[n];
    const float* s;
    if(t == 0){ li = li < 0 ? 0 : (li > NN0 - 1 ? NN0 - 1 : li); s = x0 + (size_t)li * INC; }
    else      { li = li < 0 ? 0 : (li > NN1 - 1 ? NN1 - 1 : li); s = e1 + (size_t)li * INC; }
    float4 a = ((const float4*)s)[q * 2];
    float4 c = ((const float4*)s)[q * 2 + 1];
    uint4 o;
    o.x = (unsigned)f2bf(a.x) | ((unsigned)f2bf(a.y) << 16);
    o.y = (unsigned)f2bf(a.z) | ((unsigned)f2bf(a.w) << 16);
    o.z = (unsigned)f2bf(c.x) | ((unsigned)f2bf(c.y) << 16);
    o.w = (unsigned)f2bf(c.z) | ((unsigned)f2bf(c.w) << 16);
    *(uint4*)(A + (size_t)n * RSB + 2048 + q * 16) = o;
    return;
  }
  if(b < XB + FB){
    int e = (b - XB) * 256 + threadIdx.x;
    if(e >= NE) return;
    int s = ei[e], d = ei[NE + e], t = et[e];
    int pos = atomicAdd(&deg[d], 1);
    if(pos < CAP) eb[d * CAP + pos] = s | (t << 16);
    else { int oi = atomicAdd(ovc, 1); if(oi < OVCAP) ovf[oi] = e; }
    return;
  }
  int tid = (b - XB - FB) * 256 + threadIdx.x;
  if(tid < 2 * KST * 8 * 64){
    int l = tid & 63, j = (tid >> 6) & 7, ks = (tid >> 9) % KST, v = (tid >> 9) / KST;
    int n = j * 16 + (l & 15);
    int kb = ks * 32 + (l >> 4) * 8;
    s16x8 ov;
    #pragma unroll
    for(int jj = 0; jj < 8; jj++){
      int k = kb + jj; float wv;
      if(k < 1024){ int t = k >> 7, ki = k & 127; wv = rw1[((size_t)t * HIDC + n) * INC + ki]; }
      else        { wv = qw1[((size_t)v * HIDC + n) * INC + (k - 1024)]; }
      ov[jj] = (short)f2bf(wv);
    }
    ((s16x8*)Bp1)[tid] = ov;
    return;
  }
  int tid2 = tid - 2 * KST * 8 * 64;
  if(tid2 >= 2 * KST * 3 * 64) return;
  int l = tid2 & 63;
  int q = tid2 >> 6;
  int j = q % 3; q /= 3;
  int ks = q % KST, v = q / KST;
  int n = j * 16 + (l & 15);
  int kb = ks * 32 + (l >> 4) * 8;
  s16x8 ov;
  #pragma unroll
  for(int jj = 0; jj < 8; jj++){
    int k = kb + jj; float wv = 0.f;
    if(n < OUTC){
      if(k < 1024){ int t = k >> 7, ki = k & 127; wv = rw2[((size_t)t * OUTC + n) * INC + ki]; }
      else        { wv = qw2[((size_t)v * OUTC + n) * INC + (k - 1024)]; }
    }
    ov[jj] = (short)f2bf(wv);
  }
  ((s16x8*)Bp2)[tid2] = ov;
}

// one wave per dst. Wave-uniform bucket scan: entries via scalar loads,
// source-row base in SGPRs, per-lane load = saddr + lane*4.
__global__ __launch_bounds__(256) void agg_k(const int* __restrict__ eb, const int* __restrict__ deg,
                                             char* __restrict__ A,
                                             const int* __restrict__ ovf, const int* __restrict__ ovc,
                                             const int* __restrict__ ei, const int* __restrict__ et){
  int wid = (blockIdx.x * 256 + threadIdx.x) >> 6;
  int l = threadIdx.x & 63;
  if(wid >= NN) return;
  int d = __builtin_amdgcn_readfirstlane(wid);
  int dg = deg[d];
  int nb = dg < CAP ? dg : CAP;
  const char* Af = A + 2048;
  int voff = l * 4;
  float acc[16];
  #pragma unroll
  for(int j = 0; j < 16; j++) acc[j] = 0.f;
  int c0 = 0, c1 = 0, c2 = 0, c3 = 0, c4 = 0, c5 = 0, c6 = 0, c7 = 0;

#define ACCUM(T, W) { \
  float fx_ = bflo(W), fy_ = bfhi(W); \
  switch(T){ \
    case 0: acc[0]  += fx_; acc[1]  += fy_; c0++; break; \
    case 1: acc[2]  += fx_; acc[3]  += fy_; c1++; break; \
    case 2: acc[4]  += fx_; acc[5]  += fy_; c2++; break; \
    case 3: acc[6]  += fx_; acc[7]  += fy_; c3++; break; \
    case 4: acc[8]  += fx_; acc[9]  += fy_; c4++; break; \
    case 5: acc[10] += fx_; acc[11] += fy_; c5++; break; \
    case 6: acc[12] += fx_; acc[13] += fy_; c6++; break; \
    default: acc[14] += fx_; acc[15] += fy_; c7++; break; \
  } }

  int base = d * CAP;
  int i = 0;
  for(; i + 3 < nb; i += 4){
    int p0 = eb[base + i + 0];
    int p1 = eb[base + i + 1];
    int p2 = eb[base + i + 2];
    int p3 = eb[base + i + 3];
    unsigned w0 = *(const unsigned*)(Af + (size_t)(p0 & 0xffff) * RSB + voff);
    unsigned w1 = *(const unsigned*)(Af + (size_t)(p1 & 0xffff) * RSB + voff);
    unsigned w2 = *(const unsigned*)(Af + (size_t)(p2 & 0xffff) * RSB + voff);
    unsigned w3 = *(const unsigned*)(Af + (size_t)(p3 & 0xffff) * RSB + voff);
    ACCUM(p0 >> 16, w0);
    ACCUM(p1 >> 16, w1);
    ACCUM(p2 >> 16, w2);
    ACCUM(p3 >> 16, w3);
  }
  for(; i < nb; i++){
    int p0 = eb[base + i];
    unsigned w0 = *(const unsigned*)(Af + (size_t)(p0 & 0xffff) * RSB + voff);
    ACCUM(p0 >> 16, w0);
  }
  if(dg > CAP){
    int oc = *ovc; if(oc > OVCAP) oc = OVCAP;
    for(int k = 0; k < oc; k++){
      int e = ovf[k];
      if(ei[NE + e] != d) continue;
      int s = ei[e];
      int t0 = et[e];
      unsigned w0 = *(const unsigned*)(Af + (size_t)s * RSB + voff);
      ACCUM(t0, w0);
    }
  }
#undef ACCUM

#define STORE(TT, CT) { \
    float iv = 1.0f / (float)((CT) > 1 ? (CT) : 1); \
    unsigned o = (unsigned)f2bf(acc[2*(TT)] * iv) | ((unsigned)f2bf(acc[2*(TT)+1] * iv) << 16); \
    *(unsigned*)(A + (size_t)d * RSB + (TT) * 256 + voff) = o; \
  }
  STORE(0, c0); STORE(1, c1); STORE(2, c2); STORE(3, c3);
  STORE(4, c4); STORE(5, c5); STORE(6, c6); STORE(7, c7);
#undef STORE
}

// GEMM1 split-K: 8 waves/block. wave = (row-group rg = w&3, K-half kh = w>>2).
// kh=1 waves dump acc to LDS; kh=0 waves reduce + epilogue (relu+bias -> A tail bf16).
__global__ __launch_bounds__(512) void gemm1_k(char* __restrict__ A, const s16x8* __restrict__ Bp,
                                               const float* __restrict__ rb, int nb0){
  int b = blockIdx.x;
  int v, rowbase, rowlim;
  if(b < nb0){ v = 0; rowbase = b * 64; rowlim = NN0; }
  else       { v = 1; rowbase = NN0 + (b - nb0) * 64; rowlim = NN; }
  int w = threadIdx.x >> 6, l = threadIdx.x & 63;
  int rg = w & 3, kh = w >> 2;
  int lm = l & 15, lk = l >> 4;
  int mrow = rowbase + rg * 16 + lm;
  const char* arow = A + (size_t)(mrow < NN ? mrow : NN - 1) * RSB;
  const s16x8* bv = Bp + (size_t)v * (KST * 8 * 64) + l;

  f32x4 acc[8];
  #pragma unroll
  for(int j = 0; j < 8; j++) acc[j] = (f32x4)(0.f);

  int ks0 = kh * KH;
  #pragma unroll 2
  for(int ks = ks0; ks < ks0 + KH; ks++){
    s16x8 af = *(const s16x8*)(arow + ks * 64 + lk * 16);
    const s16x8* bk = bv + (size_t)ks * (8 * 64);
    #pragma unroll
    for(int j = 0; j < 8; j++)
      acc[j] = __builtin_amdgcn_mfma_f32_16x16x32_bf16(af, bk[j * 64], acc[j], 0, 0, 0);
  }

  __shared__ f32x4 red[4][8][64];   // 32 KB
  if(kh == 1){
    #pragma unroll
    for(int j = 0; j < 8; j++) red[rg][j][l] = acc[j];
  }
  __syncthreads();
  if(kh == 0){
    #pragma unroll
    for(int j = 0; j < 8; j++){
      f32x4 o = red[rg][j][l];
      int col = j * 16 + lm;
      float bias = rb[v * HIDC + col];
      #pragma unroll
      for(int r = 0; r < 4; r++){
        int row = rowbase + rg * 16 + lk * 4 + r;
        if(row < rowlim){
          float hv = acc[j][r] + o[r] + bias;
          hv = hv > 0.f ? hv : 0.f;
          *(unsigned short*)(A + (size_t)row * RSB + 2048 + col * 2) = f2bf(hv);
        }
      }
    }
  }
}

// GEMM2 split-K + bias + log_softmax -> out (f32). Same 8-wave structure.
__global__ __launch_bounds__(512) void gemm2_k(const char* __restrict__ A, const s16x8* __restrict__ Bp,
                                               const float* __restrict__ rb, float* __restrict__ out, int nb0){
  int b = blockIdx.x;
  int v, rowbase, rowlim;
  if(b < nb0){ v = 0; rowbase = b * 64; rowlim = NN0; }
  else       { v = 1; rowbase = NN0 + (b - nb0) * 64; rowlim = NN; }
  int w = threadIdx.x >> 6, l = threadIdx.x & 63;
  int rg = w & 3, kh = w >> 2;
  int lm = l & 15, lk = l >> 4;
  int mrow = rowbase + rg * 16 + lm;
  const char* arow = A + (size_t)(mrow < NN ? mrow : NN - 1) * RSB;
  const s16x8* bv = Bp + (size_t)v * (KST * 3 * 64) + l;

  f32x4 acc[3];
  #pragma unroll
  for(int j = 0; j < 3; j++) acc[j] = (f32x4)(0.f);

  int ks0 = kh * KH;
  #pragma unroll 2
  for(int ks = ks0; ks < ks0 + KH; ks++){
    s16x8 af = *(const s16x8*)(arow + ks * 64 + lk * 16);
    const s16x8* bk = bv + (size_t)ks * (3 * 64);
    #pragma unroll
    for(int j = 0; j < 3; j++)
      acc[j] = __builtin_amdgcn_mfma_f32_16x16x32_bf16(af, bk[j * 64], acc[j], 0, 0, 0);
  }

  __shared__ f32x4 red[4][3][64];   // 12 KB
  if(kh == 1){
    #pragma unroll
    for(int j = 0; j < 3; j++) red[rg][j][l] = acc[j];
  }
  __syncthreads();
  if(kh != 0) return;

  float vals[3][4];
  #pragma unroll
  for(int j = 0; j < 3; j++){
    int col = j * 16 + lm;
    float bias = col < OUTC ? rb[v * OUTC + col] : 0.f;
    f32x4 o = red[rg][j][l];
    #pragma unroll
    for(int r = 0; r < 4; r++) vals[j][r] = acc[j][r] + o[r] + bias;
  }
  float mx[4], se[4];
  #pragma unroll
  for(int r = 0; r < 4; r++){
    float m = -1e30f;
    #pragma unroll
    for(int j = 0; j < 3; j++) if(j * 16 + lm < OUTC) m = fmaxf(m, vals[j][r]);
    mx[r] = m;
  }
  #pragma unroll
  for(int s = 1; s < 16; s <<= 1){
    #pragma unroll
    for(int r = 0; r < 4; r++) mx[r] = fmaxf(mx[r], __shfl_xor(mx[r], s, 64));
  }
  #pragma unroll
  for(int r = 0; r < 4; r++){
    float a = 0.f;
    #pragma unroll
    for(int j = 0; j < 3; j++) if(j * 16 + lm < OUTC) a += __expf(vals[j][r] - mx[r]);
    se[r] = a;
  }
  #pragma unroll
  for(int s = 1; s < 16; s <<= 1){
    #pragma unroll
    for(int r = 0; r < 4; r++) se[r] += __shfl_xor(se[r], s, 64);
  }
  #pragma unroll
  for(int r = 0; r < 4; r++) se[r] = logf(se[r]);
  #pragma unroll
  for(int j = 0; j < 3; j++){
    int col = j * 16 + lm;
    if(col >= OUTC) continue;
    #pragma unroll
    for(int r = 0; r < 4; r++){
      int row = rowbase + rg * 16 + lk * 4 + r;
      if(row < rowlim) out[(size_t)row * OUTC + col] = vals[j][r] - mx[r] - se[r];
    }
  }
}

extern "C" void kernel_launch(void* const* d_in, const int* in_sizes, int n_in,
                              void* d_out, int out_size, void* d_ws, size_t ws_size,
                              hipStream_t stream){
  const float* x0  = (const float*)d_in[0];
  const float* e1  = (const float*)d_in[1];
  const float* rw1 = (const float*)d_in[2];
  const float* qw1 = (const float*)d_in[3];
  const float* qb1 = (const float*)d_in[4];
  const float* rw2 = (const float*)d_in[5];
  const float* qw2 = (const float*)d_in[6];
  const float* qb2 = (const float*)d_in[7];
  const int*   ei  = (const int*)d_in[8];
  const int*   et  = (const int*)d_in[9];
  const int*   ntp = (const int*)d_in[10];
  const int*   lix = (const int*)d_in[11];
  float* out = (float*)d_out;

  const size_t A_OFF   = 0;             // 50000*2304 = 115,200,000
  const size_t EB_OFF  = 115200000;     // 50000*64*4 = 12,800,000
  const size_t DEG_OFF = 128000000;     // 200,000
  const size_t OVC_OFF = 128200000;     // 256
  const size_t OVF_OFF = 128200256;     // 262,144
  const size_t BP1_OFF = 128462400;     // 589,824
  const size_t BP2_OFF = 129052224;     // 221,184
  const size_t TOTAL   = 129273408;
  if(ws_size < TOTAL) return;

  char* ws = (char*)d_ws;
  char*  A   = ws + A_OFF;
  int*   eb  = (int*)(ws + EB_OFF);
  int*   deg = (int*)(ws + DEG_OFF);
  int*   ovc = (int*)(ws + OVC_OFF);
  int*   ovf = (int*)(ws + OVF_OFF);
  short* Bp1 = (short*)(ws + BP1_OFF);
  short* Bp2 = (short*)(ws + BP2_OFF);

  int nb0 = (NN0 + 63) / 64;                    // 469
  int nb1 = (NN - NN0 + 63) / 64;               // 313

  hipMemsetAsync(deg, 0, 200000 + 256, stream);           // deg + ovc (adjacent)
  build_k<<<XB + FB + PB, 256, 0, stream>>>(x0, e1, ntp, lix, A, ei, et, deg, eb, ovf, ovc,
                                            rw1, qw1, rw2, qw2, Bp1, Bp2);
  agg_k<<<(NN * 64 + 255) / 256, 256, 0, stream>>>(eb, deg, A, ovf, ovc, ei, et);
  gemm1_k<<<nb0 + nb1, 512, 0, stream>>>(A, (const s16x8*)Bp1, qb1, nb0);
  agg_k<<<(NN * 64 + 255) / 256, 256, 0, stream>>>(eb, deg, A, ovf, ovc, ei, et);
  gemm2_k<<<nb0 + nb1, 512, 0, stream>>>(A, (const s16x8*)Bp2, qb2, out, nb0);
}

// Round 8
// 304.656 us; speedup vs baseline: 1.0965x; 1.0965x over previous
//
#include <hip/hip_runtime.h>

#define NN 50000
#define NN0 30000
#define NN1 20000
#define NE 600000
#define INC 128
#define HIDC 128
#define OUTC 40
#define RSB 2304     // A row stride bytes (8*128 agg + 128 feat, bf16)
#define KST 36       // K steps of 32 (1152/32)
#define CAP 64       // bucket capacity per dst
#define OVCAP 65536
#define XB 3125      // xbuild blocks (NN*16/256)
#define FB 2344      // fill blocks (ceil(NE/256))
#define PB 198       // pack blocks

typedef __attribute__((ext_vector_type(4))) float f32x4;
typedef __attribute__((ext_vector_type(8))) short s16x8;

static __device__ __forceinline__ unsigned short f2bf(float f){
  unsigned u = __builtin_bit_cast(unsigned, f);
  u = u + 0x7fffu + ((u >> 16) & 1u);
  return (unsigned short)(u >> 16);
}
static __device__ __forceinline__ float bflo(unsigned w){
  return __builtin_bit_cast(float, w << 16);
}
static __device__ __forceinline__ float bfhi(unsigned w){
  return __builtin_bit_cast(float, w & 0xffff0000u);
}
static __device__ __forceinline__ void gll16(const void* g, void* l){
  __builtin_amdgcn_global_load_lds(
    (const __attribute__((address_space(1))) unsigned int*)g,
    (__attribute__((address_space(3))) unsigned int*)l, 16, 0, 0);
}

// fused grid: [0,XB) gather features -> A tail; [XB,XB+FB) bucket edges;
//             [XB+FB,XB+FB+PB) pack B1/B2.
__global__ void build_k(const float* __restrict__ x0, const float* __restrict__ e1,
                        const int* __restrict__ ntp, const int* __restrict__ lix,
                        char* __restrict__ A,
                        const int* __restrict__ ei, const int* __restrict__ et,
                        int* __restrict__ deg, int* __restrict__ eb,
                        int* __restrict__ ovf, int* __restrict__ ovc,
                        const float* __restrict__ rw1, const float* __restrict__ qw1,
                        const float* __restrict__ rw2, const float* __restrict__ qw2,
                        short* __restrict__ Bp1, short* __restrict__ Bp2){
  int b = blockIdx.x;
  if(b < XB){
    int tid = b * 256 + threadIdx.x;   // NN*16
    int n = tid >> 4, q = tid & 15;
    if(n >= NN) return;
    int t = ntp[n], li = lix[n];
    const float* s;
    if(t == 0){ li = li < 0 ? 0 : (li > NN0 - 1 ? NN0 - 1 : li); s = x0 + (size_t)li * INC; }
    else      { li = li < 0 ? 0 : (li > NN1 - 1 ? NN1 - 1 : li); s = e1 + (size_t)li * INC; }
    float4 a = ((const float4*)s)[q * 2];
    float4 c = ((const float4*)s)[q * 2 + 1];
    uint4 o;
    o.x = (unsigned)f2bf(a.x) | ((unsigned)f2bf(a.y) << 16);
    o.y = (unsigned)f2bf(a.z) | ((unsigned)f2bf(a.w) << 16);
    o.z = (unsigned)f2bf(c.x) | ((unsigned)f2bf(c.y) << 16);
    o.w = (unsigned)f2bf(c.z) | ((unsigned)f2bf(c.w) << 16);
    *(uint4*)(A + (size_t)n * RSB + 2048 + q * 16) = o;
    return;
  }
  if(b < XB + FB){
    int e = (b - XB) * 256 + threadIdx.x;
    if(e >= NE) return;
    int s = ei[e], d = ei[NE + e], t = et[e];
    int pos = atomicAdd(&deg[d], 1);
    if(pos < CAP) eb[d * CAP + pos] = s | (t << 16);
    else { int oi = atomicAdd(ovc, 1); if(oi < OVCAP) ovf[oi] = e; }
    return;
  }
  int tid = (b - XB - FB) * 256 + threadIdx.x;
  if(tid < 2 * KST * 8 * 64){
    int l = tid & 63, j = (tid >> 6) & 7, ks = (tid >> 9) % KST, v = (tid >> 9) / KST;
    int n = j * 16 + (l & 15);
    int kb = ks * 32 + (l >> 4) * 8;
    s16x8 ov;
    #pragma unroll
    for(int jj = 0; jj < 8; jj++){
      int k = kb + jj; float wv;
      if(k < 1024){ int t = k >> 7, ki = k & 127; wv = rw1[((size_t)t * HIDC + n) * INC + ki]; }
      else        { wv = qw1[((size_t)v * HIDC + n) * INC + (k - 1024)]; }
      ov[jj] = (short)f2bf(wv);
    }
    ((s16x8*)Bp1)[tid] = ov;
    return;
  }
  int tid2 = tid - 2 * KST * 8 * 64;
  if(tid2 >= 2 * KST * 3 * 64) return;
  int l = tid2 & 63;
  int q = tid2 >> 6;
  int j = q % 3; q /= 3;
  int ks = q % KST, v = q / KST;
  int n = j * 16 + (l & 15);
  int kb = ks * 32 + (l >> 4) * 8;
  s16x8 ov;
  #pragma unroll
  for(int jj = 0; jj < 8; jj++){
    int k = kb + jj; float wv = 0.f;
    if(n < OUTC){
      if(k < 1024){ int t = k >> 7, ki = k & 127; wv = rw2[((size_t)t * OUTC + n) * INC + ki]; }
      else        { wv = qw2[((size_t)v * OUTC + n) * INC + (k - 1024)]; }
    }
    ov[jj] = (short)f2bf(wv);
  }
  ((s16x8*)Bp2)[tid2] = ov;
}

// one wave per dst. Wave-uniform bucket scan: entries via scalar loads,
// source-row base in SGPRs, per-lane load = saddr + lane*4.
__global__ __launch_bounds__(256) void agg_k(const int* __restrict__ eb, const int* __restrict__ deg,
                                             char* __restrict__ A,
                                             const int* __restrict__ ovf, const int* __restrict__ ovc,
                                             const int* __restrict__ ei, const int* __restrict__ et){
  int wid = (blockIdx.x * 256 + threadIdx.x) >> 6;
  int l = threadIdx.x & 63;
  if(wid >= NN) return;
  int d = __builtin_amdgcn_readfirstlane(wid);
  int dg = deg[d];
  int nb = dg < CAP ? dg : CAP;
  const char* Af = A + 2048;
  int voff = l * 4;
  float acc[16];
  #pragma unroll
  for(int j = 0; j < 16; j++) acc[j] = 0.f;
  int c0 = 0, c1 = 0, c2 = 0, c3 = 0, c4 = 0, c5 = 0, c6 = 0, c7 = 0;

#define ACCUM(T, W) { \
  float fx_ = bflo(W), fy_ = bfhi(W); \
  switch(T){ \
    case 0: acc[0]  += fx_; acc[1]  += fy_; c0++; break; \
    case 1: acc[2]  += fx_; acc[3]  += fy_; c1++; break; \
    case 2: acc[4]  += fx_; acc[5]  += fy_; c2++; break; \
    case 3: acc[6]  += fx_; acc[7]  += fy_; c3++; break; \
    case 4: acc[8]  += fx_; acc[9]  += fy_; c4++; break; \
    case 5: acc[10] += fx_; acc[11] += fy_; c5++; break; \
    case 6: acc[12] += fx_; acc[13] += fy_; c6++; break; \
    default: acc[14] += fx_; acc[15] += fy_; c7++; break; \
  } }

  int base = d * CAP;
  int i = 0;
  for(; i + 3 < nb; i += 4){
    int p0 = eb[base + i + 0];
    int p1 = eb[base + i + 1];
    int p2 = eb[base + i + 2];
    int p3 = eb[base + i + 3];
    unsigned w0 = *(const unsigned*)(Af + (size_t)(p0 & 0xffff) * RSB + voff);
    unsigned w1 = *(const unsigned*)(Af + (size_t)(p1 & 0xffff) * RSB + voff);
    unsigned w2 = *(const unsigned*)(Af + (size_t)(p2 & 0xffff) * RSB + voff);
    unsigned w3 = *(const unsigned*)(Af + (size_t)(p3 & 0xffff) * RSB + voff);
    ACCUM(p0 >> 16, w0);
    ACCUM(p1 >> 16, w1);
    ACCUM(p2 >> 16, w2);
    ACCUM(p3 >> 16, w3);
  }
  for(; i < nb; i++){
    int p0 = eb[base + i];
    unsigned w0 = *(const unsigned*)(Af + (size_t)(p0 & 0xffff) * RSB + voff);
    ACCUM(p0 >> 16, w0);
  }
  if(dg > CAP){
    int oc = *ovc; if(oc > OVCAP) oc = OVCAP;
    for(int k = 0; k < oc; k++){
      int e = ovf[k];
      if(ei[NE + e] != d) continue;
      int s = ei[e];
      int t0 = et[e];
      unsigned w0 = *(const unsigned*)(Af + (size_t)s * RSB + voff);
      ACCUM(t0, w0);
    }
  }
#undef ACCUM

#define STORE(TT, CT) { \
    float iv = 1.0f / (float)((CT) > 1 ? (CT) : 1); \
    unsigned o = (unsigned)f2bf(acc[2*(TT)] * iv) | ((unsigned)f2bf(acc[2*(TT)+1] * iv) << 16); \
    *(unsigned*)(A + (size_t)d * RSB + (TT) * 256 + voff) = o; \
  }
  STORE(0, c0); STORE(1, c1); STORE(2, c2); STORE(3, c3);
  STORE(4, c4); STORE(5, c5); STORE(6, c6); STORE(7, c7);
#undef STORE
}

// GEMM1, LDS-staged double-buffered. Block: 128 rows x 128 cols, 8 waves
// (4 row-groups x 2 col-groups; wave = 32 rows x 64 cols).
// A-tile LDS layout [slot(4)][row(128)] x16B; B-tile linear [j(8)][lane(64)] x16B.
__global__ __launch_bounds__(512) void gemm1_k(char* __restrict__ A, const char* __restrict__ Bp,
                                               const float* __restrict__ rb, int nb0){
  __shared__ char lds[32768];
  int b = blockIdx.x;
  int v, rowbase, rowlim;
  if(b < nb0){ v = 0; rowbase = b * 128; rowlim = NN0; }
  else       { v = 1; rowbase = NN0 + (b - nb0) * 128; rowlim = NN; }
  int t = threadIdx.x, w = t >> 6, l = t & 63;
  int wr = w >> 1, wc = w & 1, lm = l & 15, lk = l >> 4;

  int srow = rowbase + (t & 127);
  if(srow > NN - 1) srow = NN - 1;
  const char* asrc = A + (size_t)srow * RSB + (t >> 7) * 16;   // + ks*64
  const char* bsrc = Bp + (size_t)v * 294912 + t * 16;          // + ks*8192
  char* adst = lds + t * 16;            // + cur*8192
  char* bdst = lds + 16384 + t * 16;    // + cur*8192

  f32x4 acc[2][4];
  #pragma unroll
  for(int rf = 0; rf < 2; rf++)
    #pragma unroll
    for(int cf = 0; cf < 4; cf++) acc[rf][cf] = (f32x4)(0.f);

  gll16(asrc, adst);
  gll16(bsrc, bdst);
  __syncthreads();
  int cur = 0;
  #pragma unroll 1
  for(int ks = 0; ks < KST; ks++){
    int nxt = cur ^ 1;
    if(ks + 1 < KST){
      gll16(asrc + (ks + 1) * 64, adst + nxt * 8192);
      gll16(bsrc + (size_t)(ks + 1) * 8192, bdst + nxt * 8192);
    }
    const char* ab = lds + cur * 8192;
    const char* bb = lds + 16384 + cur * 8192;
    s16x8 a0 = *(const s16x8*)(ab + (lk * 128 + wr * 32 + lm) * 16);
    s16x8 a1 = *(const s16x8*)(ab + (lk * 128 + wr * 32 + 16 + lm) * 16);
    #pragma unroll
    for(int cf = 0; cf < 4; cf++){
      s16x8 bj = *(const s16x8*)(bb + ((wc * 4 + cf) * 64 + l) * 16);
      acc[0][cf] = __builtin_amdgcn_mfma_f32_16x16x32_bf16(a0, bj, acc[0][cf], 0, 0, 0);
      acc[1][cf] = __builtin_amdgcn_mfma_f32_16x16x32_bf16(a1, bj, acc[1][cf], 0, 0, 0);
    }
    __syncthreads();
    cur = nxt;
  }
  #pragma unroll
  for(int cf = 0; cf < 4; cf++){
    int col = (wc * 4 + cf) * 16 + lm;
    float bias = rb[v * HIDC + col];
    #pragma unroll
    for(int rf = 0; rf < 2; rf++){
      #pragma unroll
      for(int r = 0; r < 4; r++){
        int row = rowbase + wr * 32 + rf * 16 + lk * 4 + r;
        if(row < rowlim){
          float hv = acc[rf][cf][r] + bias;
          hv = hv > 0.f ? hv : 0.f;
          *(unsigned short*)(A + (size_t)row * RSB + 2048 + col * 2) = f2bf(hv);
        }
      }
    }
  }
}

// GEMM2, LDS-staged + bias + log_softmax. Block: 128 rows, 8 waves (16 rows/wave),
// each wave covers all 48 cols (3 frags).
__global__ __launch_bounds__(512) void gemm2_k(const char* __restrict__ A, const char* __restrict__ Bp,
                                               const float* __restrict__ rb, float* __restrict__ out, int nb0){
  __shared__ char lds[22528];
  int b = blockIdx.x;
  int v, rowbase, rowlim;
  if(b < nb0){ v = 0; rowbase = b * 128; rowlim = NN0; }
  else       { v = 1; rowbase = NN0 + (b - nb0) * 128; rowlim = NN; }
  int t = threadIdx.x, w = t >> 6, l = t & 63;
  int lm = l & 15, lk = l >> 4;

  int srow = rowbase + (t & 127);
  if(srow > NN - 1) srow = NN - 1;
  const char* asrc = A + (size_t)srow * RSB + (t >> 7) * 16;   // + ks*64
  const char* bsrc = Bp + (size_t)v * 110592 + t * 16;          // + ks*3072
  char* adst = lds + t * 16;            // + cur*8192
  char* bdst = lds + 16384 + t * 16;    // + cur*3072 (waves 0-2 only)

  f32x4 acc[3];
  #pragma unroll
  for(int j = 0; j < 3; j++) acc[j] = (f32x4)(0.f);

  gll16(asrc, adst);
  if(w < 3) gll16(bsrc, bdst);
  __syncthreads();
  int cur = 0;
  #pragma unroll 1
  for(int ks = 0; ks < KST; ks++){
    int nxt = cur ^ 1;
    if(ks + 1 < KST){
      gll16(asrc + (ks + 1) * 64, adst + nxt * 8192);
      if(w < 3) gll16(bsrc + (size_t)(ks + 1) * 3072, bdst + nxt * 3072);
    }
    const char* ab = lds + cur * 8192;
    const char* bb = lds + 16384 + cur * 3072;
    s16x8 af = *(const s16x8*)(ab + (lk * 128 + w * 16 + lm) * 16);
    #pragma unroll
    for(int j = 0; j < 3; j++){
      s16x8 bj = *(const s16x8*)(bb + (j * 64 + l) * 16);
      acc[j] = __builtin_amdgcn_mfma_f32_16x16x32_bf16(af, bj, acc[j], 0, 0, 0);
    }
    __syncthreads();
    cur = nxt;
  }

  float vals[3][4];
  #pragma unroll
  for(int j = 0; j < 3; j++){
    int col = j * 16 + lm;
    float bias = col < OUTC ? rb[v * OUTC + col] : 0.f;
    #pragma unroll
    for(int r = 0; r < 4; r++) vals[j][r] = acc[j][r] + bias;
  }
  float mx[4], se[4];
  #pragma unroll
  for(int r = 0; r < 4; r++){
    float m = -1e30f;
    #pragma unroll
    for(int j = 0; j < 3; j++) if(j * 16 + lm < OUTC) m = fmaxf(m, vals[j][r]);
    mx[r] = m;
  }
  #pragma unroll
  for(int s = 1; s < 16; s <<= 1){
    #pragma unroll
    for(int r = 0; r < 4; r++) mx[r] = fmaxf(mx[r], __shfl_xor(mx[r], s, 64));
  }
  #pragma unroll
  for(int r = 0; r < 4; r++){
    float a = 0.f;
    #pragma unroll
    for(int j = 0; j < 3; j++) if(j * 16 + lm < OUTC) a += __expf(vals[j][r] - mx[r]);
    se[r] = a;
  }
  #pragma unroll
  for(int s = 1; s < 16; s <<= 1){
    #pragma unroll
    for(int r = 0; r < 4; r++) se[r] += __shfl_xor(se[r], s, 64);
  }
  #pragma unroll
  for(int r = 0; r < 4; r++) se[r] = logf(se[r]);
  #pragma unroll
  for(int j = 0; j < 3; j++){
    int col = j * 16 + lm;
    if(col >= OUTC) continue;
    #pragma unroll
    for(int r = 0; r < 4; r++){
      int row = rowbase + w * 16 + lk * 4 + r;
      if(row < rowlim) out[(size_t)row * OUTC + col] = vals[j][r] - mx[r] - se[r];
    }
  }
}

extern "C" void kernel_launch(void* const* d_in, const int* in_sizes, int n_in,
                              void* d_out, int out_size, void* d_ws, size_t ws_size,
                              hipStream_t stream){
  const float* x0  = (const float*)d_in[0];
  const float* e1  = (const float*)d_in[1];
  const float* rw1 = (const float*)d_in[2];
  const float* qw1 = (const float*)d_in[3];
  const float* qb1 = (const float*)d_in[4];
  const float* rw2 = (const float*)d_in[5];
  const float* qw2 = (const float*)d_in[6];
  const float* qb2 = (const float*)d_in[7];
  const int*   ei  = (const int*)d_in[8];
  const int*   et  = (const int*)d_in[9];
  const int*   ntp = (const int*)d_in[10];
  const int*   lix = (const int*)d_in[11];
  float* out = (float*)d_out;

  const size_t A_OFF   = 0;             // 50000*2304 = 115,200,000
  const size_t EB_OFF  = 115200000;     // 50000*64*4 = 12,800,000
  const size_t DEG_OFF = 128000000;     // 200,000
  const size_t OVC_OFF = 128200000;     // 256
  const size_t OVF_OFF = 128200256;     // 262,144
  const size_t BP1_OFF = 128462400;     // 589,824
  const size_t BP2_OFF = 129052224;     // 221,184
  const size_t TOTAL   = 129273408;
  if(ws_size < TOTAL) return;

  char* ws = (char*)d_ws;
  char*  A   = ws + A_OFF;
  int*   eb  = (int*)(ws + EB_OFF);
  int*   deg = (int*)(ws + DEG_OFF);
  int*   ovc = (int*)(ws + OVC_OFF);
  int*   ovf = (int*)(ws + OVF_OFF);
  short* Bp1 = (short*)(ws + BP1_OFF);
  short* Bp2 = (short*)(ws + BP2_OFF);

  int nb0 = (NN0 + 127) / 128;                  // 235
  int nb1 = (NN - NN0 + 127) / 128;             // 157

  hipMemsetAsync(deg, 0, 200000 + 256, stream);           // deg + ovc (adjacent)
  build_k<<<XB + FB + PB, 256, 0, stream>>>(x0, e1, ntp, lix, A, ei, et, deg, eb, ovf, ovc,
                                            rw1, qw1, rw2, qw2, Bp1, Bp2);
  agg_k<<<(NN * 64 + 255) / 256, 256, 0, stream>>>(eb, deg, A, ovf, ovc, ei, et);
  gemm1_k<<<nb0 + nb1, 512, 0, stream>>>(A, (const char*)Bp1, qb1, nb0);
  agg_k<<<(NN * 64 + 255) / 256, 256, 0, stream>>>(eb, deg, A, ovf, ovc, ei, et);
  gemm2_k<<<nb0 + nb1, 512, 0, stream>>>(A, (const char*)Bp2, qb2, out, nb0);
}

// Round 10
// 295.061 us; speedup vs baseline: 1.1321x; 1.0325x over previous
//
#include <hip/hip_runtime.h>

#define NN 50000
#define NN0 30000
#define NN1 20000
#define NE 600000
#define INC 128
#define HIDC 128
#define OUTC 40
#define Y1S 2304     // Y1 row stride bytes (1152 bf16: 8 rel slices + root)
#define Y2S 864      // Y2 row stride bytes (432 bf16: 9 slices of 48)
#define XS  256      // X/h row stride bytes (128 bf16)
#define CAP 64
#define OVCAP 65536
#define XB 3125      // xbuild blocks (NN*16/256)
#define FB 2344      // fill blocks
#define P1T 20480    // pack1 threads: 10 chunks * 4 ks * 8 jf * 64
#define P2T 7680     // pack2 threads: 10 chunks * 4 ks * 3 jf * 64

typedef __attribute__((ext_vector_type(4))) float f32x4;
typedef __attribute__((ext_vector_type(8))) short s16x8;

static __device__ __forceinline__ unsigned short f2bf(float f){
  unsigned u = __builtin_bit_cast(unsigned, f);
  u = u + 0x7fffu + ((u >> 16) & 1u);
  return (unsigned short)(u >> 16);
}
static __device__ __forceinline__ float bflo(unsigned w){
  return __builtin_bit_cast(float, w << 16);
}
static __device__ __forceinline__ float bfhi(unsigned w){
  return __builtin_bit_cast(float, w & 0xffff0000u);
}
static __device__ __forceinline__ void gll16(const void* g, void* l){
  __builtin_amdgcn_global_load_lds(
    (const __attribute__((address_space(1))) unsigned int*)g,
    (__attribute__((address_space(3))) unsigned int*)l, 16, 0, 0);
}

// fused grid: [0,XB) gather input features -> X (bf16);
//             [XB,XB+FB) bucket edges; rest: pack B1/B2 (bf16, MFMA layout).
__global__ void build_k(const float* __restrict__ x0, const float* __restrict__ e1,
                        const int* __restrict__ ntp, const int* __restrict__ lix,
                        char* __restrict__ Xb,
                        const int* __restrict__ ei, const int* __restrict__ et,
                        int* __restrict__ deg, int* __restrict__ eb,
                        int* __restrict__ ovf, int* __restrict__ ovc,
                        const float* __restrict__ rw1, const float* __restrict__ qw1,
                        const float* __restrict__ rw2, const float* __restrict__ qw2,
                        short* __restrict__ Bp1, short* __restrict__ Bp2){
  int b = blockIdx.x;
  if(b < XB){
    int tid = b * 256 + threadIdx.x;   // NN*16
    int n = tid >> 4, q = tid & 15;
    if(n >= NN) return;
    int t = ntp[n], li = lix[n];
    const float* s;
    if(t == 0){ li = li < 0 ? 0 : (li > NN0 - 1 ? NN0 - 1 : li); s = x0 + (size_t)li * INC; }
    else      { li = li < 0 ? 0 : (li > NN1 - 1 ? NN1 - 1 : li); s = e1 + (size_t)li * INC; }
    float4 a = ((const float4*)s)[q * 2];
    float4 c = ((const float4*)s)[q * 2 + 1];
    uint4 o;
    o.x = (unsigned)f2bf(a.x) | ((unsigned)f2bf(a.y) << 16);
    o.y = (unsigned)f2bf(a.z) | ((unsigned)f2bf(a.w) << 16);
    o.z = (unsigned)f2bf(c.x) | ((unsigned)f2bf(c.y) << 16);
    o.w = (unsigned)f2bf(c.z) | ((unsigned)f2bf(c.w) << 16);
    *(uint4*)(Xb + (size_t)n * XS + q * 16) = o;
    return;
  }
  if(b < XB + FB){
    int e = (b - XB) * 256 + threadIdx.x;
    if(e >= NE) return;
    int s = ei[e], d = ei[NE + e], t = et[e];
    int pos = atomicAdd(&deg[d], 1);
    if(pos < CAP) eb[d * CAP + pos] = s | (t << 16);
    else { int oi = atomicAdd(ovc, 1); if(oi < OVCAP) ovf[oi] = e; }
    return;
  }
  int tid = (b - XB - FB) * 256 + threadIdx.x;
  if(tid < P1T){
    // B1: chunk nc<8 = rel_w1[nc]; nc=8/9 = root_w1[0/1]. slot=((ks*8+jf)*64+l)
    int l = tid & 63, jf = (tid >> 6) & 7, ks = (tid >> 9) & 3, nc = tid >> 11;
    int cc = jf * 16 + (l & 15);
    int k0 = ks * 32 + (l >> 4) * 8;
    const float* src = (nc < 8) ? (rw1 + ((size_t)nc * HIDC + cc) * INC + k0)
                                : (qw1 + ((size_t)(nc - 8) * HIDC + cc) * INC + k0);
    s16x8 ov;
    #pragma unroll
    for(int jj = 0; jj < 8; jj++) ov[jj] = (short)f2bf(src[jj]);
    ((s16x8*)Bp1)[tid] = ov;
    return;
  }
  int tid2 = tid - P1T;
  if(tid2 >= P2T) return;
  int l = tid2 & 63;
  int q = tid2 >> 6;
  int jf = q % 3; q /= 3;
  int ks = q & 3, nc = q >> 2;
  int cc = jf * 16 + (l & 15);      // <48; cols >=40 zero-padded
  int k0 = ks * 32 + (l >> 4) * 8;
  s16x8 ov;
  #pragma unroll
  for(int jj = 0; jj < 8; jj++){
    float wv = 0.f;
    if(cc < OUTC){
      if(nc < 8) wv = rw2[((size_t)nc * OUTC + cc) * INC + k0 + jj];
      else       wv = qw2[((size_t)(nc - 8) * OUTC + cc) * INC + k0 + jj];
    }
    ov[jj] = (short)f2bf(wv);
  }
  ((s16x8*)Bp2)[tid2] = ov;
}

// T1: Y1[n, nc*128+cc] = (W_nc x_n), nc<8 rel, nc=8 root (per node type).
// Block: 128 rows x 128 cols/chunk, 9 chunks, K=128. X-tile 32KB (XOR-swizzled),
// B-chunk 32KB single-buffered. 8 waves = 4 rg x 2 cg.
__global__ __launch_bounds__(512) void t1_k(char* __restrict__ Y, const char* __restrict__ X,
                                            const char* __restrict__ Bp, int nb0){
  __shared__ char lds[65536];
  int b = blockIdx.x;
  int v, rowbase, rowlim;
  if(b < nb0){ v = 0; rowbase = b * 128; rowlim = NN0; }
  else       { v = 1; rowbase = NN0 + (b - nb0) * 128; rowlim = NN; }
  int t = threadIdx.x, w = t >> 6, l = t & 63;
  int rg = w >> 1, cg = w & 1, lm = l & 15, lk = l >> 4;
  int swz = (lm & 7) << 4;

  #pragma unroll
  for(int i = 0; i < 4; i++){
    int s = t + i * 512;
    int row = s >> 4;
    int boff = (s & 15) * 16;
    int srow = rowbase + row; if(srow > NN - 1) srow = NN - 1;
    gll16(X + (size_t)srow * XS + (boff ^ ((row & 7) << 4)), lds + s * 16);
  }
  #pragma unroll
  for(int i = 0; i < 4; i++){ int s = t + i * 512; gll16(Bp + s * 16, lds + 32768 + s * 16); }
  __syncthreads();

  for(int nc = 0; nc < 9; nc++){
    f32x4 acc[2][4];
    #pragma unroll
    for(int rf = 0; rf < 2; rf++)
      #pragma unroll
      for(int cf = 0; cf < 4; cf++) acc[rf][cf] = (f32x4)(0.f);
    #pragma unroll
    for(int ks = 0; ks < 4; ks++){
      int kb = ks * 64 + lk * 16;
      int r0 = rg * 32 + lm;
      s16x8 a0 = *(const s16x8*)(lds + r0 * 256 + (kb ^ swz));
      s16x8 a1 = *(const s16x8*)(lds + (r0 + 16) * 256 + (kb ^ swz));
      #pragma unroll
      for(int cf = 0; cf < 4; cf++){
        s16x8 bj = *(const s16x8*)(lds + 32768 + ((ks * 8 + cg * 4 + cf) * 64 + l) * 16);
        acc[0][cf] = __builtin_amdgcn_mfma_f32_16x16x32_bf16(a0, bj, acc[0][cf], 0, 0, 0);
        acc[1][cf] = __builtin_amdgcn_mfma_f32_16x16x32_bf16(a1, bj, acc[1][cf], 0, 0, 0);
      }
    }
    __syncthreads();
    if(nc < 8){
      int bnc = (nc + 1 == 8) ? (8 + v) : (nc + 1);
      const char* bs = Bp + (size_t)bnc * 32768;
      #pragma unroll
      for(int i = 0; i < 4; i++){ int s = t + i * 512; gll16(bs + s * 16, lds + 32768 + s * 16); }
    }
    #pragma unroll
    for(int cf = 0; cf < 4; cf++){
      int gcol = nc * 128 + cg * 64 + cf * 16 + lm;
      #pragma unroll
      for(int rf = 0; rf < 2; rf++){
        #pragma unroll
        for(int r = 0; r < 4; r++){
          int row = rowbase + rg * 32 + rf * 16 + lk * 4 + r;
          if(row < rowlim)
            *(unsigned short*)(Y + (size_t)row * Y1S + gcol * 2) = f2bf(acc[rf][cf][r]);
        }
      }
    }
    __syncthreads();
  }
}

// T2: Y2[n, nc*48+cc] = (W2_nc h_n). 9 chunks of 48 cols, K=128.
// 8 waves = 8 row-groups of 16; B-chunk 12KB.
__global__ __launch_bounds__(512) void t2_k(char* __restrict__ Y, const char* __restrict__ X,
                                            const char* __restrict__ Bp, int nb0){
  __shared__ char lds[45056];
  int b = blockIdx.x;
  int v, rowbase, rowlim;
  if(b < nb0){ v = 0; rowbase = b * 128; rowlim = NN0; }
  else       { v = 1; rowbase = NN0 + (b - nb0) * 128; rowlim = NN; }
  int t = threadIdx.x, w = t >> 6, l = t & 63;
  int lm = l & 15, lk = l >> 4;
  int swz = (lm & 7) << 4;

  #pragma unroll
  for(int i = 0; i < 4; i++){
    int s = t + i * 512;
    int row = s >> 4;
    int boff = (s & 15) * 16;
    int srow = rowbase + row; if(srow > NN - 1) srow = NN - 1;
    gll16(X + (size_t)srow * XS + (boff ^ ((row & 7) << 4)), lds + s * 16);
  }
  gll16(Bp + t * 16, lds + 32768 + t * 16);
  if(t < 256) gll16(Bp + (512 + t) * 16, lds + 32768 + (512 + t) * 16);
  __syncthreads();

  for(int nc = 0; nc < 9; nc++){
    f32x4 acc[3];
    #pragma unroll
    for(int j = 0; j < 3; j++) acc[j] = (f32x4)(0.f);
    #pragma unroll
    for(int ks = 0; ks < 4; ks++){
      int kb = ks * 64 + lk * 16;
      int row = w * 16 + lm;
      s16x8 af = *(const s16x8*)(lds + row * 256 + (kb ^ swz));
      #pragma unroll
      for(int jf = 0; jf < 3; jf++){
        s16x8 bj = *(const s16x8*)(lds + 32768 + ((ks * 3 + jf) * 64 + l) * 16);
        acc[jf] = __builtin_amdgcn_mfma_f32_16x16x32_bf16(af, bj, acc[jf], 0, 0, 0);
      }
    }
    __syncthreads();
    if(nc < 8){
      int bnc = (nc + 1 == 8) ? (8 + v) : (nc + 1);
      const char* bs = Bp + (size_t)bnc * 12288;
      gll16(bs + t * 16, lds + 32768 + t * 16);
      if(t < 256) gll16(bs + (512 + t) * 16, lds + 32768 + (512 + t) * 16);
    }
    #pragma unroll
    for(int jf = 0; jf < 3; jf++){
      int gcol = nc * 48 + jf * 16 + lm;
      #pragma unroll
      for(int r = 0; r < 4; r++){
        int row = rowbase + w * 16 + lk * 4 + r;
        if(row < rowlim)
          *(unsigned short*)(Y + (size_t)row * Y2S + gcol * 2) = f2bf(acc[jf][r]);
      }
    }
    __syncthreads();
  }
}

// agg1: one wave per dst. h[d] = relu(sum_t iv_t * sum_{e in t} Y1[src, t-slice]
//       + Y1[d, root] + b1[v]) -> X (bf16, overwrites input features).
__global__ __launch_bounds__(256) void agg1_k(const int* __restrict__ eb, const int* __restrict__ deg,
                                              const char* __restrict__ Y, char* __restrict__ Xh,
                                              const float* __restrict__ qb1,
                                              const int* __restrict__ ovf, const int* __restrict__ ovc,
                                              const int* __restrict__ ei, const int* __restrict__ et){
  int wid = (blockIdx.x * 256 + threadIdx.x) >> 6;
  int l = threadIdx.x & 63;
  if(wid >= NN) return;
  int d = __builtin_amdgcn_readfirstlane(wid);
  int v = d >= NN0 ? 1 : 0;
  int dg = deg[d];
  int nb = dg < CAP ? dg : CAP;
  int voff = l * 4;
  float acc[16];
  #pragma unroll
  for(int j = 0; j < 16; j++) acc[j] = 0.f;
  int c0 = 0, c1 = 0, c2 = 0, c3 = 0, c4 = 0, c5 = 0, c6 = 0, c7 = 0;

#define ACCUM(T, W) { \
  float fx_ = bflo(W), fy_ = bfhi(W); \
  switch(T){ \
    case 0: acc[0]  += fx_; acc[1]  += fy_; c0++; break; \
    case 1: acc[2]  += fx_; acc[3]  += fy_; c1++; break; \
    case 2: acc[4]  += fx_; acc[5]  += fy_; c2++; break; \
    case 3: acc[6]  += fx_; acc[7]  += fy_; c3++; break; \
    case 4: acc[8]  += fx_; acc[9]  += fy_; c4++; break; \
    case 5: acc[10] += fx_; acc[11] += fy_; c5++; break; \
    case 6: acc[12] += fx_; acc[13] += fy_; c6++; break; \
    default: acc[14] += fx_; acc[15] += fy_; c7++; break; \
  } }
#define EADDR(P) (Y + (size_t)((P) & 0xffff) * Y1S + ((((P) >> 16)) << 8) + voff)

  int base = d * CAP;
  int i = 0;
  for(; i + 3 < nb; i += 4){
    int p0 = eb[base + i + 0];
    int p1 = eb[base + i + 1];
    int p2 = eb[base + i + 2];
    int p3 = eb[base + i + 3];
    unsigned w0 = *(const unsigned*)EADDR(p0);
    unsigned w1 = *(const unsigned*)EADDR(p1);
    unsigned w2 = *(const unsigned*)EADDR(p2);
    unsigned w3 = *(const unsigned*)EADDR(p3);
    ACCUM(p0 >> 16, w0);
    ACCUM(p1 >> 16, w1);
    ACCUM(p2 >> 16, w2);
    ACCUM(p3 >> 16, w3);
  }
  for(; i < nb; i++){
    int p0 = eb[base + i];
    unsigned w0 = *(const unsigned*)EADDR(p0);
    ACCUM(p0 >> 16, w0);
  }
  if(dg > CAP){
    int oc = *ovc; if(oc > OVCAP) oc = OVCAP;
    for(int k = 0; k < oc; k++){
      int e = ovf[k];
      if(ei[NE + e] != d) continue;
      int s = ei[e], t0 = et[e];
      unsigned w0 = *(const unsigned*)(Y + (size_t)s * Y1S + t0 * 256 + voff);
      ACCUM(t0, w0);
    }
  }
#undef EADDR
#undef ACCUM

  float hx = 0.f, hy = 0.f;
#define FOLD(TT, CT) { float iv = 1.0f / (float)((CT) > 1 ? (CT) : 1); \
    hx = fmaf(acc[2*(TT)], iv, hx); hy = fmaf(acc[2*(TT)+1], iv, hy); }
  FOLD(0, c0); FOLD(1, c1); FOLD(2, c2); FOLD(3, c3);
  FOLD(4, c4); FOLD(5, c5); FOLD(6, c6); FOLD(7, c7);
#undef FOLD
  unsigned rw = *(const unsigned*)(Y + (size_t)d * Y1S + 2048 + voff);
  hx += bflo(rw); hy += bfhi(rw);
  float2 bb = *(const float2*)(qb1 + v * HIDC + 2 * l);
  hx += bb.x; hy += bb.y;
  hx = hx > 0.f ? hx : 0.f;
  hy = hy > 0.f ? hy : 0.f;
  unsigned o = (unsigned)f2bf(hx) | ((unsigned)f2bf(hy) << 16);
  *(unsigned*)(Xh + (size_t)d * XS + voff) = o;
}

// agg2: one wave per dst (24 active lanes for loads). Final bias + log_softmax -> out.
__global__ __launch_bounds__(256) void agg2_k(const int* __restrict__ eb, const int* __restrict__ deg,
                                              const char* __restrict__ Y,
                                              const float* __restrict__ qb2, float* __restrict__ outp,
                                              const int* __restrict__ ovf, const int* __restrict__ ovc,
                                              const int* __restrict__ ei, const int* __restrict__ et){
  int wid = (blockIdx.x * 256 + threadIdx.x) >> 6;
  int l = threadIdx.x & 63;
  if(wid >= NN) return;
  int d = __builtin_amdgcn_readfirstlane(wid);
  int v = d >= NN0 ? 1 : 0;
  int dg = deg[d];
  int nb = dg < CAP ? dg : CAP;
  int act = l < 24;
  int voff = l * 4;
  float acc[16];
  #pragma unroll
  for(int j = 0; j < 16; j++) acc[j] = 0.f;
  int c0 = 0, c1 = 0, c2 = 0, c3 = 0, c4 = 0, c5 = 0, c6 = 0, c7 = 0;

#define ACCUM(T, W) { \
  float fx_ = bflo(W), fy_ = bfhi(W); \
  switch(T){ \
    case 0: acc[0]  += fx_; acc[1]  += fy_; c0++; break; \
    case 1: acc[2]  += fx_; acc[3]  += fy_; c1++; break; \
    case 2: acc[4]  += fx_; acc[5]  += fy_; c2++; break; \
    case 3: acc[6]  += fx_; acc[7]  += fy_; c3++; break; \
    case 4: acc[8]  += fx_; acc[9]  += fy_; c4++; break; \
    case 5: acc[10] += fx_; acc[11] += fy_; c5++; break; \
    case 6: acc[12] += fx_; acc[13] += fy_; c6++; break; \
    default: acc[14] += fx_; acc[15] += fy_; c7++; break; \
  } }
#define ELOAD(P, W) { W = 0; if(act) W = *(const unsigned*)(Y + (size_t)((P) & 0xffff) * Y2S + ((P) >> 16) * 96 + voff); }

  int base = d * CAP;
  int i = 0;
  for(; i + 3 < nb; i += 4){
    int p0 = eb[base + i + 0];
    int p1 = eb[base + i + 1];
    int p2 = eb[base + i + 2];
    int p3 = eb[base + i + 3];
    unsigned w0, w1, w2, w3;
    ELOAD(p0, w0); ELOAD(p1, w1); ELOAD(p2, w2); ELOAD(p3, w3);
    ACCUM(p0 >> 16, w0);
    ACCUM(p1 >> 16, w1);
    ACCUM(p2 >> 16, w2);
    ACCUM(p3 >> 16, w3);
  }
  for(; i < nb; i++){
    int p0 = eb[base + i];
    unsigned w0; ELOAD(p0, w0);
    ACCUM(p0 >> 16, w0);
  }
  if(dg > CAP){
    int oc = *ovc; if(oc > OVCAP) oc = OVCAP;
    for(int k = 0; k < oc; k++){
      int e = ovf[k];
      if(ei[NE + e] != d) continue;
      int s = ei[e], t0 = et[e];
      unsigned w0 = 0;
      if(act) w0 = *(const unsigned*)(Y + (size_t)s * Y2S + t0 * 96 + voff);
      ACCUM(t0, w0);
    }
  }
#undef ELOAD
#undef ACCUM

  float vx = 0.f, vy = 0.f;
#define FOLD(TT, CT) { float iv = 1.0f / (float)((CT) > 1 ? (CT) : 1); \
    vx = fmaf(acc[2*(TT)], iv, vx); vy = fmaf(acc[2*(TT)+1], iv, vy); }
  FOLD(0, c0); FOLD(1, c1); FOLD(2, c2); FOLD(3, c3);
  FOLD(4, c4); FOLD(5, c5); FOLD(6, c6); FOLD(7, c7);
#undef FOLD
  if(act){
    unsigned rw = *(const unsigned*)(Y + (size_t)d * Y2S + 768 + voff);
    vx += bflo(rw); vy += bfhi(rw);
  }
  if(l < 20){
    float2 bb = *(const float2*)(qb2 + v * OUTC + 2 * l);
    vx += bb.x; vy += bb.y;
  }
  float mm = (l < 20) ? fmaxf(vx, vy) : -1e30f;
  #pragma unroll
  for(int s = 1; s < 64; s <<= 1) mm = fmaxf(mm, __shfl_xor(mm, s, 64));
  float ex = (l < 20) ? (__expf(vx - mm) + __expf(vy - mm)) : 0.f;
  #pragma unroll
  for(int s = 1; s < 64; s <<= 1) ex += __shfl_xor(ex, s, 64);
  float ls = logf(ex);
  if(l < 20){
    float2 o; o.x = vx - mm - ls; o.y = vy - mm - ls;
    *(float2*)(outp + (size_t)d * OUTC + 2 * l) = o;
  }
}

extern "C" void kernel_launch(void* const* d_in, const int* in_sizes, int n_in,
                              void* d_out, int out_size, void* d_ws, size_t ws_size,
                              hipStream_t stream){
  const float* x0  = (const float*)d_in[0];
  const float* e1  = (const float*)d_in[1];
  const float* rw1 = (const float*)d_in[2];
  const float* qw1 = (const float*)d_in[3];
  const float* qb1 = (const float*)d_in[4];
  const float* rw2 = (const float*)d_in[5];
  const float* qw2 = (const float*)d_in[6];
  const float* qb2 = (const float*)d_in[7];
  const int*   ei  = (const int*)d_in[8];
  const int*   et  = (const int*)d_in[9];
  const int*   ntp = (const int*)d_in[10];
  const int*   lix = (const int*)d_in[11];
  float* out = (float*)d_out;

  const size_t Y_OFF   = 0;             // 50000*2304 = 115,200,000
  const size_t X_OFF   = 115200000;     // 50000*256  = 12,800,000
  const size_t EB_OFF  = 128000000;     // 12,800,000
  const size_t DEG_OFF = 140800000;     // 200,000
  const size_t OVC_OFF = 141000000;     // 256
  const size_t OVF_OFF = 141000256;     // 262,144
  const size_t BP1_OFF = 141262400;     // 10*32768 = 327,680
  const size_t BP2_OFF = 141590080;     // 10*12288 = 122,880
  const size_t TOTAL   = 141712960;
  if(ws_size < TOTAL) return;

  char* ws = (char*)d_ws;
  char*  Y   = ws + Y_OFF;
  char*  X   = ws + X_OFF;
  int*   eb  = (int*)(ws + EB_OFF);
  int*   deg = (int*)(ws + DEG_OFF);
  int*   ovc = (int*)(ws + OVC_OFF);
  int*   ovf = (int*)(ws + OVF_OFF);
  short* Bp1 = (short*)(ws + BP1_OFF);
  short* Bp2 = (short*)(ws + BP2_OFF);

  int nb0 = (NN0 + 127) / 128;                  // 235
  int nb1 = (NN - NN0 + 127) / 128;             // 157
  int p1b = P1T / 256;                          // 80
  int p2b = P2T / 256;                          // 30

  hipMemsetAsync(deg, 0, 200000 + 256, stream);           // deg + ovc (adjacent)
  build_k<<<XB + FB + p1b + p2b, 256, 0, stream>>>(x0, e1, ntp, lix, X, ei, et, deg, eb, ovf, ovc,
                                                   rw1, qw1, rw2, qw2, Bp1, Bp2);
  t1_k<<<nb0 + nb1, 512, 0, stream>>>(Y, X, (const char*)Bp1, nb0);
  agg1_k<<<(NN + 3) / 4, 256, 0, stream>>>(eb, deg, Y, X, qb1, ovf, ovc, ei, et);
  t2_k<<<nb0 + nb1, 512, 0, stream>>>(Y, X, (const char*)Bp2, nb0);
  agg2_k<<<(NN + 3) / 4, 256, 0, stream>>>(eb, deg, Y, qb2, out, ovf, ovc, ei, et);
}